// Round 14
// baseline (350.221 us; speedup 1.0000x reference)
//
#include <hip/hip_runtime.h>
#include <hip/hip_bf16.h>

// GAT (2-layer, 8-head) on gfx950. Inputs f32 (adj int32), outputs f32.
// d_out = [h2: 2048*512 | att1: 8*2048*2048 | att2: 8*2048*2048] float32.

typedef __attribute__((ext_vector_type(8))) short bf16x8;
typedef __attribute__((ext_vector_type(4))) float f32x4;

__device__ __forceinline__ float bf2f(unsigned short u) {
    return __uint_as_float(((unsigned int)u) << 16);
}
__device__ __forceinline__ unsigned short f2bf(float f) {
    __hip_bfloat16 h = __float2bfloat16(f);
    return __builtin_bit_cast(unsigned short, h);
}
__device__ __forceinline__ float elu1(float x) { return x > 0.f ? x : expm1f(x); }

// ---------------------------------------------------------------------------
// Merged prep: grid 3072 x 256.
//  blocks [0,2048): adjbits — adj int32 -> bitmask, int4-vectorized.
//  blocks [2048,3072): reorder W1 AND W2 -> split-bf16 MFMA B-fragment packing
//                   Wp{Hi,Lo}[h][kb][col][k&31], k = kb*32 + (quad*8+j).
// ---------------------------------------------------------------------------
__global__ __launch_bounds__(256) void prep_kernel(
    const int* __restrict__ adj, unsigned long long* __restrict__ gbits,
    const float* __restrict__ W1, unsigned short* __restrict__ Wp1Hi,
    unsigned short* __restrict__ Wp1Lo,
    const float* __restrict__ W2, unsigned short* __restrict__ Wp2Hi,
    unsigned short* __restrict__ Wp2Lo) {
    const int bx  = blockIdx.x;
    const int tid = threadIdx.x;
    if (bx < 2048) {
        // 2048 blocks x 256 thr x 8 elems = 4194304 adj entries
        const int4* adj4 = reinterpret_cast<const int4*>(adj);
#pragma unroll
        for (int i = 0; i < 2; ++i) {
            int g4 = (bx * 512) + i * 256 + tid;        // int4 index
            int4 v = adj4[g4];
            unsigned long long b0 = __ballot(v.x > 0);
            unsigned long long b1 = __ballot(v.y > 0);
            unsigned long long b2 = __ballot(v.z > 0);
            unsigned long long b3 = __ballot(v.w > 0);
            int wave = tid >> 6;
            int lane = tid & 63;
            if (lane < 4) {
                int q = lane;   // word index within this wave's 4 words
                unsigned long long w0 = 0;
#pragma unroll
                for (int l = 0; l < 16; ++l) {
                    unsigned long long bit;
                    bit = (b0 >> (q * 16 + l)) & 1ull; w0 |= bit << (4 * l + 0);
                    bit = (b1 >> (q * 16 + l)) & 1ull; w0 |= bit << (4 * l + 1);
                    bit = (b2 >> (q * 16 + l)) & 1ull; w0 |= bit << (4 * l + 2);
                    bit = (b3 >> (q * 16 + l)) & 1ull; w0 |= bit << (4 * l + 3);
                }
                long ebase = 4L * (bx * 512 + i * 256 + wave * 64);
                gbits[(ebase >> 6) + q] = w0;
            }
        }
    } else {
        int i = (bx - 2048) * 256 + tid;  // 262144 threads, one elem each
        int o = i & 63;
        int k = (i >> 6) & 511;
        int h = i >> 15;
        long idx = (((h * 16) + (k >> 5)) * 64 + o) * 32 + (k & 31);
        float v1 = W1[i];
        unsigned short h1 = f2bf(v1);
        Wp1Hi[idx] = h1;
        Wp1Lo[idx] = f2bf(v1 - bf2f(h1));
        float v2 = W2[i];
        unsigned short h2 = f2bf(v2);
        Wp2Hi[idx] = h2;
        Wp2Lo[idx] = f2bf(v2 - bf2f(h2));
    }
}

// ---------------------------------------------------------------------------
// GEMM1 (HIGH-OCCUPANCY, shape verified in R9/R10 persistent kernel):
// Wh[h] = A[2048][512](f32) @ W[h][512][64], split-bf16 (3 MFMAs).
// 16-row tiles x 4-way K-split (128 each): grid = 8 heads * 128 tiles = 1024
// blocks -> 4 blocks/CU (vs previous 2). LDS-reduce the 4 K partials.
// Epilogue (wave 0): s1/s2 shfl-reduction + bf16 fragment-packed Whp.
// ---------------------------------------------------------------------------
__global__ __launch_bounds__(256, 4) void gemm1_kernel(
    const float* __restrict__ A,
    const unsigned short* __restrict__ BpHi, const unsigned short* __restrict__ BpLo,
    const float* __restrict__ avec,
    unsigned short* __restrict__ Whp, float* __restrict__ s1, float* __restrict__ s2) {
    __shared__ float accredG[4][64][20];  // [Kquarter][col][16 rows + pad]
    const int bx   = blockIdx.x;   // 1024
    const int h    = bx >> 7;
    const int mt   = bx & 127;
    const int tid  = threadIdx.x;
    const int wave = tid >> 6;     // K quarter (128 each)
    const int lane = tid & 63;
    const int quad = lane >> 4;
    const int m16  = lane & 15;
    const int rowbase = mt * 16;

    const float* Arow = A + (long)(rowbase + m16) * 512 + wave * 128 + quad * 8;
    const long boff = ((long)(h * 16 + wave * 4) * 64 + m16) * 32 + quad * 8;
    const unsigned short* BH = BpHi + boff;
    const unsigned short* BL = BpLo + boff;

    f32x4 acc[4];
#pragma unroll
    for (int t = 0; t < 4; ++t)
#pragma unroll
        for (int r = 0; r < 4; ++r) acc[t][r] = 0.f;

#pragma unroll
    for (int kb = 0; kb < 4; ++kb) {
        const float* ap = Arow + kb * 32;
        bf16x8 ahi, alo;
#pragma unroll
        for (int j = 0; j < 8; ++j) {
            float v = ap[j];
            unsigned short hv = f2bf(v);
            ahi[j] = (short)hv;
            alo[j] = (short)f2bf(v - bf2f(hv));
        }
        const unsigned short* bh0 = BH + (long)kb * 2048;
        const unsigned short* bl0 = BL + (long)kb * 2048;
#pragma unroll
        for (int t = 0; t < 4; ++t) {
            bf16x8 bh = *reinterpret_cast<const bf16x8*>(bh0 + t * 512);
            bf16x8 bl = *reinterpret_cast<const bf16x8*>(bl0 + t * 512);
            acc[t] = __builtin_amdgcn_mfma_f32_16x16x32_bf16(alo, bh, acc[t], 0, 0, 0);
            acc[t] = __builtin_amdgcn_mfma_f32_16x16x32_bf16(ahi, bl, acc[t], 0, 0, 0);
            acc[t] = __builtin_amdgcn_mfma_f32_16x16x32_bf16(ahi, bh, acc[t], 0, 0, 0);
        }
    }

#pragma unroll
    for (int t = 0; t < 4; ++t)
        *reinterpret_cast<f32x4*>(&accredG[wave][t * 16 + m16][quad * 4]) = acc[t];
    __syncthreads();
    if (wave != 0) return;

#pragma unroll
    for (int w = 1; w < 4; ++w)
#pragma unroll
        for (int t = 0; t < 4; ++t) {
            f32x4 o = *reinterpret_cast<const f32x4*>(&accredG[w][t * 16 + m16][quad * 4]);
#pragma unroll
            for (int r = 0; r < 4; ++r) acc[t][r] += o[r];
        }

    // ---- s1/s2 epilogue ----
    float aS[4], aD[4];
#pragma unroll
    for (int t = 0; t < 4; ++t) {
        aS[t] = avec[(h << 7) + t * 16 + m16];
        aD[t] = avec[(h << 7) + 64 + t * 16 + m16];
    }
#pragma unroll
    for (int r = 0; r < 4; ++r) {
        float t1 = 0.f, t2 = 0.f;
#pragma unroll
        for (int t = 0; t < 4; ++t) {
            float v = acc[t][r];
            t1 = fmaf(v, aS[t], t1);
            t2 = fmaf(v, aD[t], t2);
        }
#pragma unroll
        for (int off = 1; off < 16; off <<= 1) {
            t1 += __shfl_xor(t1, off);
            t2 += __shfl_xor(t2, off);
        }
        if (m16 == 0) {
            int row = rowbase + quad * 4 + r;
            s1[(h << 11) + row] = t1;
            s2[(h << 11) + row] = t2;
        }
    }

    // ---- store Wh bf16 fragment-packed (Hi only; PV tolerates bf16) ----
#pragma unroll
    for (int t = 0; t < 4; ++t) {
        const int col = t * 16 + m16;
#pragma unroll
        for (int r = 0; r < 4; ++r) {
            const int row = rowbase + quad * 4 + r;
            long idx = (((long)(h * 64 + (row >> 5)) * 64 + col) << 5) + (row & 31);
            Whp[idx] = f2bf(acc[t][r]);
        }
    }
}

// ---------------------------------------------------------------------------
// Fused attention, 2 passes (R12 structure = empirical best):
//  P12: ONLINE masked softmax scan (exact per-row max + sum in one pass).
//  P3 : stage -> FLUSH (NT stores lead the MFMA cluster) -> PV MFMA.
// Block = 256 thr (4 waves), 16 rows; each wave owns a j-quarter.
// ---------------------------------------------------------------------------
__global__ __launch_bounds__(256, 4) void fused_att_kernel(
    const float* __restrict__ s1g, const float* __restrict__ s2g,
    const unsigned int* __restrict__ gbits,
    const unsigned short* __restrict__ Whp,
    float* __restrict__ att, float* __restrict__ hout) {
    __shared__ unsigned int lbits[16 * 65];   // 16 rows x 64 words, +1 pad
    __shared__ float ls2[2048];
    __shared__ float lmax[4][16];
    __shared__ float lsum[4][16];
    __shared__ float accred[3][64][20];       // waves 1..3 partial PV
    __shared__ f32x4 pstage[4][16][9];        // per-wave P staging

    const int bx   = blockIdx.x;   // 1024
    const int h    = bx >> 7;
    const int row0 = (bx & 127) << 4;
    const int tid  = threadIdx.x;
    const int wq   = tid >> 6;     // wave = j-quarter
    const int lane = tid & 63;
    const int quad = lane >> 4;
    const int m16  = lane & 15;

    // stage adj bits (16 rows x 64 words) + s2 (2048 f32)
#pragma unroll
    for (int i = 0; i < 4; ++i) {
        int idx = i * 256 + tid;
        lbits[(idx >> 6) * 65 + (idx & 63)] = gbits[((row0 + (idx >> 6)) << 6) + (idx & 63)];
    }
    const float4* s2v4 = reinterpret_cast<const float4*>(s2g + (h << 11));
#pragma unroll
    for (int i = 0; i < 2; ++i) {
        int idx = i * 256 + tid;
        reinterpret_cast<float4*>(ls2)[idx] = s2v4[idx];
    }
    __syncthreads();

    const float s1i = s1g[(h << 11) + row0 + m16];

    // ---- P12: fused online masked max+sum over this wave's 16 words ----
    float mx = -INFINITY;
    float lp = 0.f;
#pragma unroll 2
    for (int i = 0; i < 16; ++i) {
        const int jt = wq * 16 + i;
        unsigned int word = lbits[m16 * 65 + jt] >> (quad * 8);
        float4 sa = *reinterpret_cast<const float4*>(ls2 + jt * 32 + quad * 8);
        float4 sb = *reinterpret_cast<const float4*>(ls2 + jt * 32 + quad * 8 + 4);
        float sv[8] = {sa.x, sa.y, sa.z, sa.w, sb.x, sb.y, sb.z, sb.w};
        float ev[8];
        float bm = -INFINITY;
#pragma unroll
        for (int u = 0; u < 8; ++u) {
            float e = s1i + sv[u];
            e = fmaxf(e, 0.2f * e);
            ev[u] = e;
            bm = fmaxf(bm, ((word >> u) & 1u) ? e : -INFINITY);
        }
        float nm = fmaxf(mx, bm);
        float sc = (mx == nm) ? 1.f : __expf(mx - nm);  // -inf==-inf -> 1 (no NaN)
        lp *= sc;
        mx = nm;
#pragma unroll
        for (int u = 0; u < 8; ++u)
            lp += ((word >> u) & 1u) ? __expf(ev[u] - mx) : 0.f;
    }
    // merge across the 4 quads of each row (lanes l, l^16, l^32, l^48)
#pragma unroll
    for (int off = 16; off < 64; off <<= 1) {
        float omx = __shfl_xor(mx, off);
        float olp = __shfl_xor(lp, off);
        float nm = fmaxf(mx, omx);
        float sa = (mx == nm) ? 1.f : __expf(mx - nm);
        float sb = (omx == nm) ? 1.f : __expf(omx - nm);
        lp = fmaf(lp, sa, olp * sb);
        mx = nm;
    }
    if (lane < 16) {
        lmax[wq][m16] = mx;
        lsum[wq][m16] = lp;
    }
    __syncthreads();
    // block-level merge over the 4 wave-quarters
    float m = fmaxf(fmaxf(lmax[0][m16], lmax[1][m16]),
                    fmaxf(lmax[2][m16], lmax[3][m16]));
    float l = 0.f;
#pragma unroll
    for (int w = 0; w < 4; ++w) {
        float wm = lmax[w][m16];
        float ws = (wm == m) ? 1.f : __expf(wm - m);
        l = fmaf(lsum[w][m16], ws, l);
    }
    const bool am = (m == -INFINITY);          // all-masked row
    const float invl = am ? 0.f : 1.f / l;
    const float fallb = 1.f / 2048.f;

    // ---- P3: att write (stage -> flush -> MFMA; stores lead compute) ----
    f32x4 acc[4];
#pragma unroll
    for (int t = 0; t < 4; ++t)
#pragma unroll
        for (int r = 0; r < 4; ++r) acc[t][r] = 0.f;

    const unsigned short* BW = Whp + ((long)(h << 12) + m16) * 32 + quad * 8;
    float* attbase = att + (long)h * 4194304 + (long)row0 * 2048;
    const int fr = lane >> 3;        // flush row within half (0..7)
    const int fc = lane & 7;         // flush col-block (16B units)

#pragma unroll 2
    for (int i = 0; i < 16; ++i) {
        const int jt = wq * 16 + i;
        unsigned int word = lbits[m16 * 65 + jt];
        float4 sa = *reinterpret_cast<const float4*>(ls2 + jt * 32 + quad * 8);
        float4 sb = *reinterpret_cast<const float4*>(ls2 + jt * 32 + quad * 8 + 4);
        float sv[8] = {sa.x, sa.y, sa.z, sa.w, sb.x, sb.y, sb.z, sb.w};
        float p[8];
        bf16x8 af;
#pragma unroll
        for (int u = 0; u < 8; ++u) {
            float e = s1i + sv[u];
            e = fmaxf(e, 0.2f * e);
            float pv = ((word >> (quad * 8 + u)) & 1u) ? __expf(e - m) * invl : 0.f;
            p[u] = am ? fallb : pv;
            af[u] = (short)f2bf(p[u]);
        }
        // stage P-tile (fragment layout -> row-major) in this wave's LDS region
        f32x4 plo, phi;
        plo[0] = p[0]; plo[1] = p[1]; plo[2] = p[2]; plo[3] = p[3];
        phi[0] = p[4]; phi[1] = p[5]; phi[2] = p[6]; phi[3] = p[7];
        pstage[wq][m16][quad * 2]     = plo;
        pstage[wq][m16][quad * 2 + 1] = phi;

        // packed flush FIRST (within-wave LDS RAW; lgkmcnt-ordered, no barrier):
        // 2 wave-stores, each 8 rows x 128B full lines (NT) — in flight during MFMA
#pragma unroll
        for (int half = 0; half < 2; ++half) {
            const int r = half * 8 + fr;
            f32x4 v = pstage[wq][r][fc];
            __builtin_nontemporal_store(
                v, reinterpret_cast<f32x4*>(attbase + (long)r * 2048 + jt * 32 + fc * 4));
        }

        const unsigned short* b0 = BW + (long)jt * 2048;
#pragma unroll
        for (int t = 0; t < 4; ++t) {
            bf16x8 bf = *reinterpret_cast<const bf16x8*>(b0 + t * 512);
            acc[t] = __builtin_amdgcn_mfma_f32_16x16x32_bf16(af, bf, acc[t], 0, 0, 0);
        }
    }

    // ---- reduce partial PV across waves, epilogue by wave 0 ----
    if (wq > 0) {
#pragma unroll
        for (int t = 0; t < 4; ++t)
            *reinterpret_cast<f32x4*>(&accred[wq - 1][t * 16 + m16][quad * 4]) = acc[t];
    }
    __syncthreads();
    if (wq == 0) {
#pragma unroll
        for (int t = 0; t < 4; ++t) {
            const int col = t * 16 + m16;
#pragma unroll
            for (int w = 0; w < 3; ++w) {
                f32x4 o = *reinterpret_cast<const f32x4*>(&accred[w][col][quad * 4]);
#pragma unroll
                for (int r = 0; r < 4; ++r) acc[t][r] += o[r];
            }
#pragma unroll
            for (int r = 0; r < 4; ++r) {
                const int row = row0 + quad * 4 + r;
                hout[(row << 9) + (h << 6) + col] = elu1(elu1(acc[t][r]));
            }
        }
    }
}

// ---------------------------------------------------------------------------
extern "C" void kernel_launch(void* const* d_in, const int* in_sizes, int n_in,
                              void* d_out, int out_size, void* d_ws, size_t ws_size,
                              hipStream_t stream) {
    const float* x  = (const float*)d_in[0];   // [2048][512]
    const int* adj  = (const int*)d_in[1];     // [2048][2048]
    const float* W1 = (const float*)d_in[2];   // [8][512][64]
    const float* a1 = (const float*)d_in[3];   // [8][128]
    const float* W2 = (const float*)d_in[4];
    const float* a2 = (const float*)d_in[5];

    float* out  = (float*)d_out;       // h2 [2048][512]
    float* att1 = out + 1048576;       // [8][2048][2048]
    float* att2 = att1 + 33554432;

    char* w = (char*)d_ws;
    unsigned short* Wp1Hi = (unsigned short*)(w);             // 512 KB
    unsigned short* Wp1Lo = (unsigned short*)(w + 524288);    // 512 KB
    unsigned short* Wp2Hi = (unsigned short*)(w + 1048576);   // 512 KB
    unsigned short* Wp2Lo = (unsigned short*)(w + 1572864);   // 512 KB
    unsigned short* Whp   = (unsigned short*)(w + 2097152);   // 2 MB
    float* s1             = (float*)(w + 4194304);            // 64 KB
    float* s2             = (float*)(w + 4259840);            // 64 KB
    unsigned long long* gbits = (unsigned long long*)(w + 4325376);  // 512 KB
    float* x2             = (float*)(w + 4849664);            // 4 MB -> ends ~8.6 MB

    const unsigned int* gbits32 = (const unsigned int*)gbits;

    // merged prep: adjbits (vectorized) + W1/W2 reorder in ONE dispatch
    prep_kernel<<<3072, 256, 0, stream>>>(adj, gbits, W1, Wp1Hi, Wp1Lo,
                                          W2, Wp2Hi, Wp2Lo);

    // ---- layer 1 ----
    gemm1_kernel<<<1024, 256, 0, stream>>>(x, Wp1Hi, Wp1Lo, a1, Whp, s1, s2);
    fused_att_kernel<<<1024, 256, 0, stream>>>(s1, s2, gbits32, Whp, att1, x2);

    // ---- layer 2 ----
    gemm1_kernel<<<1024, 256, 0, stream>>>(x2, Wp2Hi, Wp2Lo, a2, Whp, s1, s2);
    fused_att_kernel<<<1024, 256, 0, stream>>>(s1, s2, gbits32, Whp, att2, out);
}